// Round 3
// baseline (222.908 us; speedup 1.0000x reference)
//
#include <hip/hip_runtime.h>

#define NB 2048
#define DD 128
#define HH 256
#define KF 32768   /* HH*DD, kappa = h*128+d == original Wh row index */
#define LN_EPS 1e-5f
#define KSPLIT 32
#define KSL (KF / KSPLIT)   /* 1024 = 8 h-values x 128 d */

typedef __attribute__((ext_vector_type(8))) short short8;
typedef __attribute__((ext_vector_type(4))) float float4_t;
typedef __attribute__((ext_vector_type(4))) float f4;

__device__ __forceinline__ unsigned short f2bf(float f) {
    unsigned int u = __builtin_bit_cast(unsigned int, f);
    u += 0x7fffu + ((u >> 16) & 1u);   // RNE
    return (unsigned short)(u >> 16);
}

__device__ __forceinline__ unsigned int pkbf(float lo, float hi) {
    unsigned int r;
    asm("v_cvt_pk_bf16_f32 %0, %1, %2" : "=v"(r) : "v"(lo), "v"(hi));
    return r;
}

__device__ __forceinline__ void gl2lds16(const void* g, void* l) {
    __builtin_amdgcn_global_load_lds(
        (const __attribute__((address_space(1))) unsigned int*)g,
        (__attribute__((address_space(3))) unsigned int*)l, 16, 0, 0);
}

// ---------------------------------------------------------------------------
// Kernel 1: stats (blocks 0..1023) + Win/bin transpose (1024..1087) +
// bias2 zero (1088) + Cacc zero (1089..1344).
// ---------------------------------------------------------------------------
__global__ void stats_k(const float* __restrict__ arr, const float* __restrict__ Win,
                        const float* __restrict__ bin, float2* __restrict__ stats,
                        float* __restrict__ WinT, float* __restrict__ binT,
                        float* __restrict__ bias2, float* __restrict__ Cacc) {
    __shared__ float a_s[2][128];
    __shared__ float tile[32][33];
    int bid = blockIdx.x;
    int t = threadIdx.x;

    if (bid >= 1024) {
        if (bid == 1088) { bias2[t] = 0.f; return; }
        if (bid >= 1089) {                 // zero Cacc: 256 blocks x 2048 floats
            float* p = Cacc + (long)(bid - 1089) * 2048 + t * 8;
            *(f4*)p = (f4){0.f, 0.f, 0.f, 0.f};
            *(f4*)(p + 4) = (f4){0.f, 0.f, 0.f, 0.f};
            return;
        }
        int tid = bid - 1024;         // 0..63
        int mat = tid >> 5;           // 0: Win, 1: bin
        int dt = (tid >> 3) & 3;      // d-tile 0..3
        int ht = tid & 7;             // h-tile 0..7
        const float* src = mat ? bin : Win;
        float* dst = mat ? binT : WinT;
        int c = t & 31, r = t >> 5;   // 32 x 8
#pragma unroll
        for (int rr = r; rr < 32; rr += 8)
            tile[rr][c] = src[(dt * 32 + rr) * 256 + ht * 32 + c];
        __syncthreads();
#pragma unroll
        for (int rr = r; rr < 32; rr += 8)
            dst[(ht * 32 + rr) * 128 + dt * 32 + c] = tile[c][rr];
        return;
    }

    int n0 = bid * 2;
    if (t < 256) a_s[t >> 7][t & 127] = arr[n0 * 128 + t];
    __syncthreads();
    int h = t;
    float sum[2] = {0.f, 0.f}, ssq[2] = {0.f, 0.f};
    for (int d = 0; d < 128; ++d) {
        float w = Win[d * 256 + h];
        float bb = bin[d * 256 + h];
#pragma unroll
        for (int q = 0; q < 2; ++q) {
            float x = fmaxf(fmaf(a_s[q][d], w, bb), 0.f);
            sum[q] += x;
            ssq[q] = fmaf(x, x, ssq[q]);
        }
    }
#pragma unroll
    for (int q = 0; q < 2; ++q) {
        float mu = sum[q] * (1.f / 128.f);
        float var = fmaxf(ssq[q] * (1.f / 128.f) - mu * mu, 0.f);
        float rs = rsqrtf(var + LN_EPS);
        stats[(long)(n0 + q) * HH + h] = make_float2(rs, mu * rs);
    }
}

// ---------------------------------------------------------------------------
// Kernel 2: WhbT[j][k] = bf16(g[d]*Wh[k][j]), k = h*128+d (plain transpose),
// plus bias2[j] += sum_k beta[d(k)]*Wh[k][j].
// ---------------------------------------------------------------------------
__global__ void prep_b(const float* __restrict__ Wh, const float* __restrict__ g,
                       const float* __restrict__ beta, unsigned short* __restrict__ WhbT,
                       float* __restrict__ bias2) {
    __shared__ unsigned short tile[64][65];
    __shared__ float red[4][64];
    int kb = blockIdx.x;          // k-tile 0..511
    int jb = blockIdx.y;          // j-tile 0..3
    int t = threadIdx.x;
    int c = t & 63, r4 = t >> 6;
    int k0 = kb * 64;
    float bsum = 0.f;
    for (int rr = r4; rr < 64; rr += 4) {
        int k = k0 + rr, d = k & 127;
        float v = Wh[(long)k * 256 + jb * 64 + c];
        tile[rr][c] = f2bf(g[d] * v);
        bsum = fmaf(beta[d], v, bsum);
    }
    __syncthreads();
    for (int rr = r4; rr < 64; rr += 4)
        WhbT[(long)(jb * 64 + rr) * KF + k0 + c] = tile[c][rr];
    red[r4][c] = bsum;
    __syncthreads();
    if (r4 == 0)
        atomicAdd(&bias2[jb * 64 + c], red[0][c] + red[1][c] + red[2][c] + red[3][c]);
}

// ---------------------------------------------------------------------------
// Kernel 3: fused GEMM, 512 threads (8 waves, 4m x 2n), BM=128, BN=256,
// BK=32, KSPLIT=32.  Per wave: mi=2 m-frags x ni=8 n-frags (z replication
// R=2, was 4).  All per-step operands (Win/bin slice, stats slice) staged to
// LDS in the prologue -- steady-state steps touch global only via the B
// global_load_lds (staged one step ahead, one barrier per step).  Epilogue
// atomicAdds into Cacc (2 MB) -- no 64 MB Cp round-trip.
// ---------------------------------------------------------------------------
__global__ __launch_bounds__(512, 4) void gemm_f(
        const float* __restrict__ arr, const float* __restrict__ WinT,
        const float* __restrict__ binT, const float2* __restrict__ stats,
        const unsigned short* __restrict__ Bt,   // WhbT [256][KF]
        float* __restrict__ Cacc) {
    __shared__ unsigned short Bs[2][256 * 32];   // 2 x 16KB ping-pong
    __shared__ float Ws[8 * 128];                // Win slice [h_local][d]
    __shared__ float Vs[8 * 128];                // bin slice
    __shared__ float2 Ss[128 * 9];               // stats slice, pad to 9
    int bid = blockIdx.x;
    int mt = bid & 15;
    int ks = bid >> 4;          // 0..31
    int m0 = mt * 128;
    long k0 = (long)ks * KSL;
    int h0 = ks * 8;
    int t = threadIdx.x;
    int lane = t & 63, wave = t >> 6;
    int wm = (wave >> 1) * 32;       // 4 m-groups of 32 rows
    int wn = (wave & 1) * 128;       // 2 n-groups of 128 cols
    int fr = lane & 15;
    int kch = lane >> 4;             // 0..3  (16B k-chunk)
    int fk8 = kch * 8;

    float4_t acc[2][8] = {};

    const unsigned short* Bab = Bt + k0;
    // staging: 16KB tile, 512 threads x 2 slots of 16B; slot s -> (j=s>>2, kc=s&3)
    long boff0 = (long)(t >> 2) * KF + (long)(t & 3) * 8;
    long boff1 = boff0 + 128l * KF;

    // prologue: Win/bin slice, stats slice, B tile 0
    if (t < 256) {
        *(f4*)&Ws[t * 4] = *(const f4*)(WinT + h0 * 128 + t * 4);
    } else {
        *(f4*)&Vs[(t - 256) * 4] = *(const f4*)(binT + h0 * 128 + (t - 256) * 4);
    }
    {
        int sr = t >> 2, sc = (t & 3) * 2;
        const float2* sp = stats + (long)(m0 + sr) * HH + h0 + sc;
        float2 v0 = sp[0], v1 = sp[1];
        Ss[sr * 9 + sc] = v0;
        Ss[sr * 9 + sc + 1] = v1;
    }
    gl2lds16(Bab + boff0, &Bs[0][t * 8]);
    gl2lds16(Bab + boff1, &Bs[0][(t + 512) * 8]);

    int row0 = m0 + wm + fr;         // global row of m-frag 0; frag 1 = +16
    f4 aa[2][2];
    __syncthreads();

    for (int it = 0; it < 32; ++it) {
        int q = it >> 3, hl = it & 7, cur = it & 1;
        // stage next B tile first: maximum slack before the end barrier
        if (it < 31) {
            int itn = it + 1;
            int kap = (itn & 7) * 128 + (itn >> 3) * 32;
            gl2lds16(Bab + kap + boff0, &Bs[cur ^ 1][t * 8]);
            gl2lds16(Bab + kap + boff1, &Bs[cur ^ 1][(t + 512) * 8]);
        }
        if (hl == 0) {
#pragma unroll
            for (int mi = 0; mi < 2; ++mi) {
                const float* ap = arr + (long)(row0 + mi * 16) * DD + q * 32 + fk8;
                aa[mi][0] = *(const f4*)ap;
                aa[mi][1] = *(const f4*)(ap + 4);
            }
        }
        // per-step operands from LDS (w/v wave-broadcast: 4 addrs/wave)
        int wb = hl * 128 + q * 32 + fk8;
        f4 w0 = *(const f4*)&Ws[wb], w1 = *(const f4*)&Ws[wb + 4];
        f4 v0 = *(const f4*)&Vs[wb], v1 = *(const f4*)&Vs[wb + 4];
        // z-gen in registers -> A fragments
        short8 af[2];
#pragma unroll
        for (int mi = 0; mi < 2; ++mi) {
            float2 sv = Ss[(wm + mi * 16 + fr) * 9 + hl];
            float rs = sv.x, nm = -sv.y;
            float z0 = fmaf(fmaxf(fmaf(aa[mi][0][0], w0[0], v0[0]), 0.f), rs, nm);
            float z1 = fmaf(fmaxf(fmaf(aa[mi][0][1], w0[1], v0[1]), 0.f), rs, nm);
            float z2 = fmaf(fmaxf(fmaf(aa[mi][0][2], w0[2], v0[2]), 0.f), rs, nm);
            float z3 = fmaf(fmaxf(fmaf(aa[mi][0][3], w0[3], v0[3]), 0.f), rs, nm);
            float z4 = fmaf(fmaxf(fmaf(aa[mi][1][0], w1[0], v1[0]), 0.f), rs, nm);
            float z5 = fmaf(fmaxf(fmaf(aa[mi][1][1], w1[1], v1[1]), 0.f), rs, nm);
            float z6 = fmaf(fmaxf(fmaf(aa[mi][1][2], w1[2], v1[2]), 0.f), rs, nm);
            float z7 = fmaf(fmaxf(fmaf(aa[mi][1][3], w1[3], v1[3]), 0.f), rs, nm);
            union { short8 s; unsigned int u[4]; } pk;
            pk.u[0] = pkbf(z0, z1);
            pk.u[1] = pkbf(z2, z3);
            pk.u[2] = pkbf(z4, z5);
            pk.u[3] = pkbf(z6, z7);
            af[mi] = pk.s;
        }
        // B fragments + MFMA, ni in 2 halves (register pressure)
#pragma unroll
        for (int half = 0; half < 2; ++half) {
            short8 bfv[4];
#pragma unroll
            for (int n4 = 0; n4 < 4; ++n4) {
                int j = wn + (half * 4 + n4) * 16 + fr;
                bfv[n4] = *(const short8*)&Bs[cur][j * 32 + fk8];
            }
#pragma unroll
            for (int mi = 0; mi < 2; ++mi)
#pragma unroll
                for (int n4 = 0; n4 < 4; ++n4)
                    acc[mi][half * 4 + n4] = __builtin_amdgcn_mfma_f32_16x16x32_bf16(
                        af[mi], bfv[n4], acc[mi][half * 4 + n4], 0, 0, 0);
        }
        if (it < 31) __syncthreads();
    }

    // epilogue: C/D layout col=lane&15, row=(lane>>4)*4+reg  [m89-verified]
    int rb = (lane >> 4) * 4;
#pragma unroll
    for (int mi = 0; mi < 2; ++mi) {
#pragma unroll
        for (int ni = 0; ni < 8; ++ni) {
            int n = wn + ni * 16 + fr;
#pragma unroll
            for (int r = 0; r < 4; ++r) {
                int m = m0 + wm + mi * 16 + rb + r;
                atomicAdd(&Cacc[(long)m * 256 + n], acc[mi][ni][r]);
            }
        }
    }
}

// ---------------------------------------------------------------------------
// Kernel 4: out[n] = bo + sum_j Wo[j]*relu(bh[j] + bias2[j] + Cacc[n][j])
// ---------------------------------------------------------------------------
__global__ void finale(const float* __restrict__ Cacc, const float* __restrict__ bh,
                       const float* __restrict__ Wo, const float* __restrict__ bo,
                       const float* __restrict__ bias2, float* __restrict__ out) {
    __shared__ float red[4];
    int n = blockIdx.x, t = threadIdx.x;
    int lane = t & 63, wave = t >> 6;
    float s = bh[t] + bias2[t] + Cacc[(long)n * 256 + t];
    float v = fmaxf(s, 0.f) * Wo[t];
#pragma unroll
    for (int o = 32; o; o >>= 1) v += __shfl_down(v, o);
    if (lane == 0) red[wave] = v;
    __syncthreads();
    if (t == 0) out[n] = red[0] + red[1] + red[2] + red[3] + bo[0];
}

extern "C" void kernel_launch(void* const* d_in, const int* in_sizes, int n_in,
                              void* d_out, int out_size, void* d_ws, size_t ws_size,
                              hipStream_t stream) {
    const float* arr  = (const float*)d_in[0];
    const float* Win  = (const float*)d_in[1];
    const float* bin  = (const float*)d_in[2];
    const float* ln_g = (const float*)d_in[7];
    const float* ln_b = (const float*)d_in[8];
    const float* Wh   = (const float*)d_in[9];
    const float* bh   = (const float*)d_in[10];
    const float* Wo   = (const float*)d_in[11];
    const float* bo   = (const float*)d_in[12];
    float* out = (float*)d_out;

    char* ws = (char*)d_ws;
    unsigned short* WhbT = (unsigned short*)ws;                    // 16,777,216 B
    float2* stats = (float2*)(ws + 16777216ull);                   //  4,194,304 B
    float* Cacc   = (float*)(ws + 20971520ull);                    //  2,097,152 B
    float* WinT   = (float*)(ws + 23068672ull);                    //    131,072 B
    float* binT   = (float*)(ws + 23199744ull);                    //    131,072 B
    float* bias2  = (float*)(ws + 23330816ull);                    //      1,024 B

    hipLaunchKernelGGL(stats_k, dim3(1345), dim3(256), 0, stream,
                       arr, Win, bin, stats, WinT, binT, bias2, Cacc);
    hipLaunchKernelGGL(prep_b, dim3(512, 4), dim3(256), 0, stream,
                       Wh, ln_g, ln_b, WhbT, bias2);
    hipLaunchKernelGGL(gemm_f, dim3(512), dim3(512), 0, stream,
                       arr, WinT, binT, stats, WhbT, Cacc);
    hipLaunchKernelGGL(finale, dim3(NB), dim3(256), 0, stream,
                       Cacc, bh, Wo, bo, bias2, out);
}

// Round 4
// 196.192 us; speedup vs baseline: 1.1362x; 1.1362x over previous
//
#include <hip/hip_runtime.h>

#define NB 2048
#define DD 128
#define HH 256
#define KF 32768   /* HH*DD, kappa = h*128+d == original Wh row index */
#define LN_EPS 1e-5f
#define KSPLIT 32
#define KSL (KF / KSPLIT)   /* 1024 = 8 h-values x 128 d */

typedef __attribute__((ext_vector_type(8))) short short8;
typedef __attribute__((ext_vector_type(4))) float float4_t;
typedef __attribute__((ext_vector_type(4))) float f4;

__device__ __forceinline__ unsigned short f2bf(float f) {
    unsigned int u = __builtin_bit_cast(unsigned int, f);
    u += 0x7fffu + ((u >> 16) & 1u);   // RNE
    return (unsigned short)(u >> 16);
}

__device__ __forceinline__ unsigned int pkbf(float lo, float hi) {
    unsigned int r;
    asm("v_cvt_pk_bf16_f32 %0, %1, %2" : "=v"(r) : "v"(lo), "v"(hi));
    return r;
}

__device__ __forceinline__ void gl2lds16(const void* g, void* l) {
    __builtin_amdgcn_global_load_lds(
        (const __attribute__((address_space(1))) unsigned int*)g,
        (__attribute__((address_space(3))) unsigned int*)l, 16, 0, 0);
}

// ---------------------------------------------------------------------------
// Kernel 1: stats (blocks 0..1023) + Win/bin transpose (1024..1087) +
// bias2 zero (1088).
// ---------------------------------------------------------------------------
__global__ void stats_k(const float* __restrict__ arr, const float* __restrict__ Win,
                        const float* __restrict__ bin, float2* __restrict__ stats,
                        float* __restrict__ WinT, float* __restrict__ binT,
                        float* __restrict__ bias2) {
    __shared__ float a_s[2][128];
    __shared__ float tile[32][33];
    int bid = blockIdx.x;
    int t = threadIdx.x;

    if (bid >= 1024) {
        if (bid == 1088) { bias2[t] = 0.f; return; }
        int tid = bid - 1024;         // 0..63
        int mat = tid >> 5;           // 0: Win, 1: bin
        int dt = (tid >> 3) & 3;      // d-tile 0..3
        int ht = tid & 7;             // h-tile 0..7
        const float* src = mat ? bin : Win;
        float* dst = mat ? binT : WinT;
        int c = t & 31, r = t >> 5;   // 32 x 8
#pragma unroll
        for (int rr = r; rr < 32; rr += 8)
            tile[rr][c] = src[(dt * 32 + rr) * 256 + ht * 32 + c];
        __syncthreads();
#pragma unroll
        for (int rr = r; rr < 32; rr += 8)
            dst[(ht * 32 + rr) * 128 + dt * 32 + c] = tile[c][rr];
        return;
    }

    int n0 = bid * 2;
    if (t < 256) a_s[t >> 7][t & 127] = arr[n0 * 128 + t];
    __syncthreads();
    int h = t;
    float sum[2] = {0.f, 0.f}, ssq[2] = {0.f, 0.f};
    for (int d = 0; d < 128; ++d) {
        float w = Win[d * 256 + h];
        float bb = bin[d * 256 + h];
#pragma unroll
        for (int q = 0; q < 2; ++q) {
            float x = fmaxf(fmaf(a_s[q][d], w, bb), 0.f);
            sum[q] += x;
            ssq[q] = fmaf(x, x, ssq[q]);
        }
    }
#pragma unroll
    for (int q = 0; q < 2; ++q) {
        float mu = sum[q] * (1.f / 128.f);
        float var = fmaxf(ssq[q] * (1.f / 128.f) - mu * mu, 0.f);
        float rs = rsqrtf(var + LN_EPS);
        stats[(long)(n0 + q) * HH + h] = make_float2(rs, mu * rs);
    }
}

// ---------------------------------------------------------------------------
// Kernel 2: WhbT[j][k] = bf16(g[d]*Wh[k][j]), k = h*128+d (plain transpose),
// plus bias2[j] += sum_k beta[d(k)]*Wh[k][j].
// ---------------------------------------------------------------------------
__global__ void prep_b(const float* __restrict__ Wh, const float* __restrict__ g,
                       const float* __restrict__ beta, unsigned short* __restrict__ WhbT,
                       float* __restrict__ bias2) {
    __shared__ unsigned short tile[64][65];
    __shared__ float red[4][64];
    int kb = blockIdx.x;          // k-tile 0..511
    int jb = blockIdx.y;          // j-tile 0..3
    int t = threadIdx.x;
    int c = t & 63, r4 = t >> 6;
    int k0 = kb * 64;
    float bsum = 0.f;
    for (int rr = r4; rr < 64; rr += 4) {
        int k = k0 + rr, d = k & 127;
        float v = Wh[(long)k * 256 + jb * 64 + c];
        tile[rr][c] = f2bf(g[d] * v);
        bsum = fmaf(beta[d], v, bsum);
    }
    __syncthreads();
    for (int rr = r4; rr < 64; rr += 4)
        WhbT[(long)(jb * 64 + rr) * KF + k0 + c] = tile[c][rr];
    red[r4][c] = bsum;
    __syncthreads();
    if (r4 == 0)
        atomicAdd(&bias2[jb * 64 + c], red[0][c] + red[1][c] + red[2][c] + red[3][c]);
}

// ---------------------------------------------------------------------------
// Kernel 3: fused GEMM, 512 threads (8 waves, 4m x 2n), BM=128, BN=256,
// BK=32, KSPLIT=32.  XCD-AWARE bid map: xcd = bid&7 owns 4 consecutive
// k-slices, so the 16 blocks sharing a B-slice all live on ONE XCD and the
// slice stays in that XCD's L2 (round-3 scatter cost ~110 MB of refetch).
// Epilogue: plain coalesced stores to split-K partials Cp (no atomics).
// ---------------------------------------------------------------------------
__global__ __launch_bounds__(512, 4) void gemm_f(
        const float* __restrict__ arr, const float* __restrict__ WinT,
        const float* __restrict__ binT, const float2* __restrict__ stats,
        const unsigned short* __restrict__ Bt,   // WhbT [256][KF]
        float* __restrict__ Cp) {
    __shared__ unsigned short Bs[2][256 * 32];   // 2 x 16KB ping-pong
    __shared__ float Ws[8 * 128];                // Win slice [h_local][d]
    __shared__ float Vs[8 * 128];                // bin slice
    __shared__ float2 Ss[128 * 9];               // stats slice, pad to 9
    int bid = blockIdx.x;
    int xcd = bid & 7;
    int idx = bid >> 3;           // 0..63 within XCD
    int ks = xcd * 4 + (idx >> 4);   // 4 k-slices per XCD
    int mt = idx & 15;
    int m0 = mt * 128;
    long k0 = (long)ks * KSL;
    int h0 = ks * 8;
    int t = threadIdx.x;
    int lane = t & 63, wave = t >> 6;
    int wm = (wave >> 1) * 32;       // 4 m-groups of 32 rows
    int wn = (wave & 1) * 128;       // 2 n-groups of 128 cols
    int fr = lane & 15;
    int kch = lane >> 4;             // 0..3  (16B k-chunk)
    int fk8 = kch * 8;

    float4_t acc[2][8] = {};

    const unsigned short* Bab = Bt + k0;
    // staging: 16KB tile, 512 threads x 2 slots of 16B; slot s -> (j=s>>2, kc=s&3)
    long boff0 = (long)(t >> 2) * KF + (long)(t & 3) * 8;
    long boff1 = boff0 + 128l * KF;

    // prologue: Win/bin slice, stats slice, B tile 0
    if (t < 256) {
        *(f4*)&Ws[t * 4] = *(const f4*)(WinT + h0 * 128 + t * 4);
    } else {
        *(f4*)&Vs[(t - 256) * 4] = *(const f4*)(binT + h0 * 128 + (t - 256) * 4);
    }
    {
        int sr = t >> 2, sc = (t & 3) * 2;
        const float2* sp = stats + (long)(m0 + sr) * HH + h0 + sc;
        float2 v0 = sp[0], v1 = sp[1];
        Ss[sr * 9 + sc] = v0;
        Ss[sr * 9 + sc + 1] = v1;
    }
    gl2lds16(Bab + boff0, &Bs[0][t * 8]);
    gl2lds16(Bab + boff1, &Bs[0][(t + 512) * 8]);

    int row0 = m0 + wm + fr;         // global row of m-frag 0; frag 1 = +16
    f4 aa[2][2];
    __syncthreads();

    for (int it = 0; it < 32; ++it) {
        int q = it >> 3, hl = it & 7, cur = it & 1;
        // stage next B tile first: maximum slack before the end barrier
        if (it < 31) {
            int itn = it + 1;
            int kap = (itn & 7) * 128 + (itn >> 3) * 32;
            gl2lds16(Bab + kap + boff0, &Bs[cur ^ 1][t * 8]);
            gl2lds16(Bab + kap + boff1, &Bs[cur ^ 1][(t + 512) * 8]);
        }
        if (hl == 0) {
#pragma unroll
            for (int mi = 0; mi < 2; ++mi) {
                const float* ap = arr + (long)(row0 + mi * 16) * DD + q * 32 + fk8;
                aa[mi][0] = *(const f4*)ap;
                aa[mi][1] = *(const f4*)(ap + 4);
            }
        }
        // per-step operands from LDS (w/v wave-broadcast: 4 addrs/wave)
        int wb = hl * 128 + q * 32 + fk8;
        f4 w0 = *(const f4*)&Ws[wb], w1 = *(const f4*)&Ws[wb + 4];
        f4 v0 = *(const f4*)&Vs[wb], v1 = *(const f4*)&Vs[wb + 4];
        // z-gen in registers -> A fragments
        short8 af[2];
#pragma unroll
        for (int mi = 0; mi < 2; ++mi) {
            float2 sv = Ss[(wm + mi * 16 + fr) * 9 + hl];
            float rs = sv.x, nm = -sv.y;
            float z0 = fmaf(fmaxf(fmaf(aa[mi][0][0], w0[0], v0[0]), 0.f), rs, nm);
            float z1 = fmaf(fmaxf(fmaf(aa[mi][0][1], w0[1], v0[1]), 0.f), rs, nm);
            float z2 = fmaf(fmaxf(fmaf(aa[mi][0][2], w0[2], v0[2]), 0.f), rs, nm);
            float z3 = fmaf(fmaxf(fmaf(aa[mi][0][3], w0[3], v0[3]), 0.f), rs, nm);
            float z4 = fmaf(fmaxf(fmaf(aa[mi][1][0], w1[0], v1[0]), 0.f), rs, nm);
            float z5 = fmaf(fmaxf(fmaf(aa[mi][1][1], w1[1], v1[1]), 0.f), rs, nm);
            float z6 = fmaf(fmaxf(fmaf(aa[mi][1][2], w1[2], v1[2]), 0.f), rs, nm);
            float z7 = fmaf(fmaxf(fmaf(aa[mi][1][3], w1[3], v1[3]), 0.f), rs, nm);
            union { short8 s; unsigned int u[4]; } pk;
            pk.u[0] = pkbf(z0, z1);
            pk.u[1] = pkbf(z2, z3);
            pk.u[2] = pkbf(z4, z5);
            pk.u[3] = pkbf(z6, z7);
            af[mi] = pk.s;
        }
        // B fragments + MFMA, ni in 2 halves (register pressure)
#pragma unroll
        for (int half = 0; half < 2; ++half) {
            short8 bfv[4];
#pragma unroll
            for (int n4 = 0; n4 < 4; ++n4) {
                int j = wn + (half * 4 + n4) * 16 + fr;
                bfv[n4] = *(const short8*)&Bs[cur][j * 32 + fk8];
            }
#pragma unroll
            for (int mi = 0; mi < 2; ++mi)
#pragma unroll
                for (int n4 = 0; n4 < 4; ++n4)
                    acc[mi][half * 4 + n4] = __builtin_amdgcn_mfma_f32_16x16x32_bf16(
                        af[mi], bfv[n4], acc[mi][half * 4 + n4], 0, 0, 0);
        }
        if (it < 31) __syncthreads();
    }

    // epilogue: coalesced stores to split-K partial; C/D layout col=lane&15,
    // row=(lane>>4)*4+reg  [m89-verified]
    int rb = (lane >> 4) * 4;
    float* Cb = Cp + (long)ks * NB * 256;
#pragma unroll
    for (int mi = 0; mi < 2; ++mi) {
#pragma unroll
        for (int ni = 0; ni < 8; ++ni) {
            int n = wn + ni * 16 + fr;
#pragma unroll
            for (int r = 0; r < 4; ++r) {
                int m = m0 + wm + mi * 16 + rb + r;
                Cb[(long)m * 256 + n] = acc[mi][ni][r];
            }
        }
    }
}

// ---------------------------------------------------------------------------
// Kernel 4: out[n] = bo + sum_j Wo[j]*relu(bh[j] + bias2[j] + sum_s Cp[s][n][j])
// ---------------------------------------------------------------------------
__global__ void finale(const float* __restrict__ Cp, const float* __restrict__ bh,
                       const float* __restrict__ Wo, const float* __restrict__ bo,
                       const float* __restrict__ bias2, float* __restrict__ out) {
    __shared__ float red[4];
    int n = blockIdx.x, t = threadIdx.x;
    int lane = t & 63, wave = t >> 6;
    float s = bh[t] + bias2[t];
    for (int sl = 0; sl < KSPLIT; ++sl)
        s += Cp[(long)sl * NB * 256 + (long)n * 256 + t];
    float v = fmaxf(s, 0.f) * Wo[t];
#pragma unroll
    for (int o = 32; o; o >>= 1) v += __shfl_down(v, o);
    if (lane == 0) red[wave] = v;
    __syncthreads();
    if (t == 0) out[n] = red[0] + red[1] + red[2] + red[3] + bo[0];
}

extern "C" void kernel_launch(void* const* d_in, const int* in_sizes, int n_in,
                              void* d_out, int out_size, void* d_ws, size_t ws_size,
                              hipStream_t stream) {
    const float* arr  = (const float*)d_in[0];
    const float* Win  = (const float*)d_in[1];
    const float* bin  = (const float*)d_in[2];
    const float* ln_g = (const float*)d_in[7];
    const float* ln_b = (const float*)d_in[8];
    const float* Wh   = (const float*)d_in[9];
    const float* bh   = (const float*)d_in[10];
    const float* Wo   = (const float*)d_in[11];
    const float* bo   = (const float*)d_in[12];
    float* out = (float*)d_out;

    char* ws = (char*)d_ws;
    unsigned short* WhbT = (unsigned short*)ws;                    // 16,777,216 B
    float2* stats = (float2*)(ws + 16777216ull);                   //  4,194,304 B
    float* Cp     = (float*)(ws + 20971520ull);                    // 67,108,864 B
    float* WinT   = (float*)(ws + 88080384ull);                    //    131,072 B
    float* binT   = (float*)(ws + 88211456ull);                    //    131,072 B
    float* bias2  = (float*)(ws + 88342528ull);                    //      1,024 B

    hipLaunchKernelGGL(stats_k, dim3(1089), dim3(256), 0, stream,
                       arr, Win, bin, stats, WinT, binT, bias2);
    hipLaunchKernelGGL(prep_b, dim3(512, 4), dim3(256), 0, stream,
                       Wh, ln_g, ln_b, WhbT, bias2);
    hipLaunchKernelGGL(gemm_f, dim3(512), dim3(512), 0, stream,
                       arr, WinT, binT, stats, WhbT, Cp);
    hipLaunchKernelGGL(finale, dim3(NB), dim3(256), 0, stream,
                       Cp, bh, Wo, bo, bias2, out);
}

// Round 7
// 178.571 us; speedup vs baseline: 1.2483x; 1.0987x over previous
//
#include <hip/hip_runtime.h>

#define NB 2048
#define DD 128
#define HH 256
#define KF 32768   /* HH*DD, kappa = h*128+d == original Wh row index */
#define LN_EPS 1e-5f
#define KSPLIT 32
#define KSL (KF / KSPLIT)   /* 1024 = 8 h-values x 128 d */

typedef __attribute__((ext_vector_type(8))) short short8;
typedef __attribute__((ext_vector_type(4))) float float4_t;
typedef __attribute__((ext_vector_type(4))) float f4;

__device__ __forceinline__ unsigned short f2bf(float f) {
    unsigned int u = __builtin_bit_cast(unsigned int, f);
    u += 0x7fffu + ((u >> 16) & 1u);   // RNE
    return (unsigned short)(u >> 16);
}

__device__ __forceinline__ unsigned int pkbf(float lo, float hi) {
    unsigned int r;
    asm("v_cvt_pk_bf16_f32 %0, %1, %2" : "=v"(r) : "v"(lo), "v"(hi));
    return r;
}

__device__ __forceinline__ void gl2lds16(const void* g, void* l) {
    __builtin_amdgcn_global_load_lds(
        (const __attribute__((address_space(1))) unsigned int*)g,
        (__attribute__((address_space(3))) unsigned int*)l, 16, 0, 0);
}

// ---------------------------------------------------------------------------
// Kernel 1 (fused): blocks 0..511 stats (n-batch 4, round-1-verified logic);
// 512..575 Win/bin transpose (round-1-verified); 576..2623 prep_b
// (round-2..4-verified; bias2 zeroed by hipMemsetAsync before this kernel).
// ---------------------------------------------------------------------------
__global__ void prep_all(const float* __restrict__ arr, const float* __restrict__ Win,
                         const float* __restrict__ bin, const float* __restrict__ Wh,
                         const float* __restrict__ g, const float* __restrict__ beta,
                         float2* __restrict__ stats, float* __restrict__ WinT,
                         float* __restrict__ binT, unsigned short* __restrict__ WhbT,
                         float* __restrict__ bias2) {
    __shared__ float a_s[4][128];
    __shared__ float tile32[32][33];
    __shared__ unsigned short tile64[64][65];
    __shared__ float red[4][64];
    int bid = blockIdx.x;
    int t = threadIdx.x;

    if (bid >= 576) {                  // ---- prep_b part ----
        int pid = bid - 576;
        int kb = pid >> 2;             // 0..511
        int jb = pid & 3;              // 0..3
        int c = t & 63, r4 = t >> 6;
        int k0 = kb * 64;
        float bsum = 0.f;
        for (int rr = r4; rr < 64; rr += 4) {
            int k = k0 + rr, d = k & 127;
            float v = Wh[(long)k * 256 + jb * 64 + c];
            tile64[rr][c] = f2bf(g[d] * v);
            bsum = fmaf(beta[d], v, bsum);
        }
        __syncthreads();
        for (int rr = r4; rr < 64; rr += 4)
            WhbT[(long)(jb * 64 + rr) * KF + k0 + c] = tile64[c][rr];
        red[r4][c] = bsum;
        __syncthreads();
        if (r4 == 0)
            atomicAdd(&bias2[jb * 64 + c],
                      red[0][c] + red[1][c] + red[2][c] + red[3][c]);
        return;
    }
    if (bid >= 512) {                  // ---- Win/bin transpose part ----
        int tid = bid - 512;           // 0..63
        int mat = tid >> 5;            // 0: Win, 1: bin
        int dt = (tid >> 3) & 3;       // d-tile 0..3
        int ht = tid & 7;              // h-tile 0..7
        const float* src = mat ? bin : Win;
        float* dst = mat ? binT : WinT;
        int c = t & 31, r = t >> 5;    // 32 x 8
#pragma unroll
        for (int rr = r; rr < 32; rr += 8)
            tile32[rr][c] = src[(dt * 32 + rr) * 256 + ht * 32 + c];
        __syncthreads();
#pragma unroll
        for (int rr = r; rr < 32; rr += 8)
            dst[(ht * 32 + rr) * 128 + dt * 32 + c] = tile32[c][rr];
        return;
    }
    // ---- stats part, n-batch 4 (round-1-verified) ----
    int n0 = bid * 4;
    for (int i = t; i < 512; i += 256) a_s[i >> 7][i & 127] = arr[n0 * 128 + i];
    __syncthreads();
    int h = t;
    float sum[4] = {0.f, 0.f, 0.f, 0.f}, ssq[4] = {0.f, 0.f, 0.f, 0.f};
    for (int d = 0; d < 128; ++d) {
        float w = Win[d * 256 + h];
        float bb = bin[d * 256 + h];
#pragma unroll
        for (int q = 0; q < 4; ++q) {
            float x = fmaxf(fmaf(a_s[q][d], w, bb), 0.f);
            sum[q] += x;
            ssq[q] = fmaf(x, x, ssq[q]);
        }
    }
#pragma unroll
    for (int q = 0; q < 4; ++q) {
        float mu = sum[q] * (1.f / 128.f);
        float var = fmaxf(ssq[q] * (1.f / 128.f) - mu * mu, 0.f);
        float rs = rsqrtf(var + LN_EPS);
        stats[(long)(n0 + q) * HH + h] = make_float2(rs, mu * rs);
    }
}

// ---------------------------------------------------------------------------
// Kernel 2: fused GEMM -- BYTE-IDENTICAL to round-4's passing gemm_f.
// 512 threads (8 waves, 4m x 2n), BM=128, BN=256, BK=32, KSPLIT=32.
// XCD-aware bid map; B staged one step ahead (ping-pong, one barrier/step);
// linear staging + linear reads; plain coalesced stores to split-K partials.
// ---------------------------------------------------------------------------
__global__ __launch_bounds__(512, 4) void gemm_f(
        const float* __restrict__ arr, const float* __restrict__ WinT,
        const float* __restrict__ binT, const float2* __restrict__ stats,
        const unsigned short* __restrict__ Bt,   // WhbT [256][KF]
        float* __restrict__ Cp) {
    __shared__ unsigned short Bs[2][256 * 32];   // 2 x 16KB ping-pong
    __shared__ float Ws[8 * 128];                // Win slice [h_local][d]
    __shared__ float Vs[8 * 128];                // bin slice
    __shared__ float2 Ss[128 * 9];               // stats slice, pad to 9
    int bid = blockIdx.x;
    int xcd = bid & 7;
    int idx = bid >> 3;              // 0..63
    int ks = xcd * 4 + (idx >> 4);   // 0..31, 4 slices per XCD
    int mt = idx & 15;
    int m0 = mt * 128;
    long k0 = (long)ks * KSL;
    int h0 = ks * 8;
    int t = threadIdx.x;
    int lane = t & 63, wave = t >> 6;
    int wm = (wave >> 1) * 32;       // 4 m-groups of 32 rows
    int wn = (wave & 1) * 128;       // 2 n-groups of 128 cols
    int fr = lane & 15;
    int fk8 = (lane >> 4) * 8;

    float4_t acc[2][8] = {};

    const unsigned short* Bab = Bt + k0;
    long boff0 = (long)(t >> 2) * KF + (long)(t & 3) * 8;
    long boff1 = boff0 + 128l * KF;

    // prologue: Win/bin slice (4KB each), stats slice, B tile 0
    if (t < 256) {
        *(f4*)&Ws[t * 4] = *(const f4*)(WinT + h0 * 128 + t * 4);
    } else {
        *(f4*)&Vs[(t - 256) * 4] = *(const f4*)(binT + h0 * 128 + (t - 256) * 4);
    }
    {
        int sr = t >> 2, sc = (t & 3) * 2;
        const float2* sp = stats + (long)(m0 + sr) * HH + h0 + sc;
        float2 v0 = sp[0], v1 = sp[1];
        Ss[sr * 9 + sc] = v0;
        Ss[sr * 9 + sc + 1] = v1;
    }
    gl2lds16(Bab + boff0, &Bs[0][t * 8]);
    gl2lds16(Bab + boff1, &Bs[0][(t + 512) * 8]);

    int row0 = m0 + wm + fr;         // global row of m-frag 0; frag 1 = +16
    f4 aa[2][2];
    __syncthreads();

    for (int it = 0; it < 32; ++it) {
        int q = it >> 3, hl = it & 7, cur = it & 1;
        // stage next B tile first: maximum slack before the end barrier
        if (it < 31) {
            int itn = it + 1;
            long kap = (itn & 7) * 128 + (itn >> 3) * 32;
            gl2lds16(Bab + kap + boff0, &Bs[cur ^ 1][t * 8]);
            gl2lds16(Bab + kap + boff1, &Bs[cur ^ 1][(t + 512) * 8]);
        }
        if (hl == 0) {
#pragma unroll
            for (int mi = 0; mi < 2; ++mi) {
                const float* ap = arr + (long)(row0 + mi * 16) * DD + q * 32 + fk8;
                aa[mi][0] = *(const f4*)ap;
                aa[mi][1] = *(const f4*)(ap + 4);
            }
        }
        // per-step operands from LDS (w/v wave-broadcast, conflict-free)
        int wb = hl * 128 + q * 32 + fk8;
        f4 w0 = *(const f4*)&Ws[wb], w1 = *(const f4*)&Ws[wb + 4];
        f4 v0 = *(const f4*)&Vs[wb], v1 = *(const f4*)&Vs[wb + 4];
        // z-gen in registers -> A fragments
        short8 af[2];
#pragma unroll
        for (int mi = 0; mi < 2; ++mi) {
            float2 sv = Ss[(wm + mi * 16 + fr) * 9 + hl];
            float rs = sv.x, nm = -sv.y;
            float z0 = fmaf(fmaxf(fmaf(aa[mi][0][0], w0[0], v0[0]), 0.f), rs, nm);
            float z1 = fmaf(fmaxf(fmaf(aa[mi][0][1], w0[1], v0[1]), 0.f), rs, nm);
            float z2 = fmaf(fmaxf(fmaf(aa[mi][0][2], w0[2], v0[2]), 0.f), rs, nm);
            float z3 = fmaf(fmaxf(fmaf(aa[mi][0][3], w0[3], v0[3]), 0.f), rs, nm);
            float z4 = fmaf(fmaxf(fmaf(aa[mi][1][0], w1[0], v1[0]), 0.f), rs, nm);
            float z5 = fmaf(fmaxf(fmaf(aa[mi][1][1], w1[1], v1[1]), 0.f), rs, nm);
            float z6 = fmaf(fmaxf(fmaf(aa[mi][1][2], w1[2], v1[2]), 0.f), rs, nm);
            float z7 = fmaf(fmaxf(fmaf(aa[mi][1][3], w1[3], v1[3]), 0.f), rs, nm);
            union { short8 s; unsigned int u[4]; } pk;
            pk.u[0] = pkbf(z0, z1);
            pk.u[1] = pkbf(z2, z3);
            pk.u[2] = pkbf(z4, z5);
            pk.u[3] = pkbf(z6, z7);
            af[mi] = pk.s;
        }
        // B fragments + MFMA, ni in 2 halves (register pressure)
#pragma unroll
        for (int half = 0; half < 2; ++half) {
            short8 bfv[4];
#pragma unroll
            for (int n4 = 0; n4 < 4; ++n4) {
                int j = wn + (half * 4 + n4) * 16 + fr;
                bfv[n4] = *(const short8*)&Bs[cur][j * 32 + fk8];
            }
#pragma unroll
            for (int mi = 0; mi < 2; ++mi)
#pragma unroll
                for (int n4 = 0; n4 < 4; ++n4)
                    acc[mi][half * 4 + n4] = __builtin_amdgcn_mfma_f32_16x16x32_bf16(
                        af[mi], bfv[n4], acc[mi][half * 4 + n4], 0, 0, 0);
        }
        if (it < 31) __syncthreads();
    }

    // epilogue: coalesced stores to split-K partial; C/D layout col=lane&15,
    // row=(lane>>4)*4+reg  [m89-verified]
    int rb = (lane >> 4) * 4;
    float* Cb = Cp + (long)ks * NB * 256;
#pragma unroll
    for (int mi = 0; mi < 2; ++mi) {
#pragma unroll
        for (int ni = 0; ni < 8; ++ni) {
            int n = wn + ni * 16 + fr;
#pragma unroll
            for (int r = 0; r < 4; ++r) {
                int m = m0 + wm + mi * 16 + rb + r;
                Cb[(long)m * 256 + n] = acc[mi][ni][r];
            }
        }
    }
}

// ---------------------------------------------------------------------------
// Kernel 3: out[n] = bo + sum_j Wo[j]*relu(bh[j]+bias2[j]+sum_s Cp[s][n][j])
// BYTE-IDENTICAL to round-4's passing finale.
// ---------------------------------------------------------------------------
__global__ void finale(const float* __restrict__ Cp, const float* __restrict__ bh,
                       const float* __restrict__ Wo, const float* __restrict__ bo,
                       const float* __restrict__ bias2, float* __restrict__ out) {
    __shared__ float red[4];
    int n = blockIdx.x, t = threadIdx.x;
    int lane = t & 63, wave = t >> 6;
    float s = bh[t] + bias2[t];
    for (int sl = 0; sl < KSPLIT; ++sl)
        s += Cp[(long)sl * NB * 256 + (long)n * 256 + t];
    float v = fmaxf(s, 0.f) * Wo[t];
#pragma unroll
    for (int o = 32; o; o >>= 1) v += __shfl_down(v, o);
    if (lane == 0) red[wave] = v;
    __syncthreads();
    if (t == 0) out[n] = red[0] + red[1] + red[2] + red[3] + bo[0];
}

extern "C" void kernel_launch(void* const* d_in, const int* in_sizes, int n_in,
                              void* d_out, int out_size, void* d_ws, size_t ws_size,
                              hipStream_t stream) {
    const float* arr  = (const float*)d_in[0];
    const float* Win  = (const float*)d_in[1];
    const float* bin  = (const float*)d_in[2];
    const float* ln_g = (const float*)d_in[7];
    const float* ln_b = (const float*)d_in[8];
    const float* Wh   = (const float*)d_in[9];
    const float* bh   = (const float*)d_in[10];
    const float* Wo   = (const float*)d_in[11];
    const float* bo   = (const float*)d_in[12];
    float* out = (float*)d_out;

    char* ws = (char*)d_ws;
    unsigned short* WhbT = (unsigned short*)ws;                    // 16,777,216 B
    float2* stats = (float2*)(ws + 16777216ull);                   //  4,194,304 B
    float* Cp     = (float*)(ws + 20971520ull);                    // 67,108,864 B
    float* WinT   = (float*)(ws + 88080384ull);                    //    131,072 B
    float* binT   = (float*)(ws + 88211456ull);                    //    131,072 B
    float* bias2  = (float*)(ws + 88342528ull);                    //      1,024 B

    hipMemsetAsync(bias2, 0, 1024, stream);
    hipLaunchKernelGGL(prep_all, dim3(2624), dim3(256), 0, stream,
                       arr, Win, bin, Wh, ln_g, ln_b, stats, WinT, binT, WhbT, bias2);
    hipLaunchKernelGGL(gemm_f, dim3(512), dim3(512), 0, stream,
                       arr, WinT, binT, stats, WhbT, Cp);
    hipLaunchKernelGGL(finale, dim3(NB), dim3(256), 0, stream,
                       Cp, bh, Wo, bo, bias2, out);
}